// Round 9
// baseline (126.808 us; speedup 1.0000x reference)
//
#include <hip/hip_runtime.h>
#include <math.h>

// B=4, N=512, C=D=256, K=20, rows=2048
//
// ws layout (float offsets):
//   WtL   [0, 65536)         W_l^T [c][d]      (transpose -> proj)
//   WtR   [65536, 131072)
//   alpha [0, 1048576)       [row][512]        (pair -> topk, overlaps Wt: sequential)
//   XL    [1048576, +524288) [row][d]
//   XRt   [1572864, +524288) [b][d][j] d-major
//   Av    [2097152, +2048)
//   Bv    [2099200, +2048)
//
// out (float): [0,40960) index_i | [40960,81920) index_j | [81920,122880) attention

#define GLD_LDS(gp, lp)                                                        \
    __builtin_amdgcn_global_load_lds(                                          \
        (const __attribute__((address_space(1))) float*)(gp),                  \
        (__attribute__((address_space(3))) float*)(lp), 16, 0, 0)

// s_waitcnt imm (gfx9): vmcnt[3:0]|[15:14], expcnt[6:4], lgkmcnt[11:8]
#define WAIT_VM8   __builtin_amdgcn_s_waitcnt(0x0F78)  // vmcnt(8)
#define WAIT_VM0   __builtin_amdgcn_s_waitcnt(0x0F70)  // vmcnt(0)
#define WAIT_LGKM0 __builtin_amdgcn_s_waitcnt(0xC07F)  // lgkmcnt(0)

__global__ __launch_bounds__(256) void k_transpose(const float* __restrict__ Wl,
                                                   const float* __restrict__ Wr,
                                                   float* __restrict__ WtL,
                                                   float* __restrict__ WtR) {
    const int d = blockIdx.x, c = threadIdx.x;
    if (blockIdx.y == 0) WtL[c * 256 + d] = Wl[d * 256 + c];
    else                 WtR[c * 256 + d] = Wr[d * 256 + c];
}

// 256 wgs x 512 thr; wg = 8 rows; dq = tid&63, rq = bit6, ch = tid>>7 (c-quarter).
// v4: W loads in bursts of 16 b128 (deep L2 queue); (512,1) frees the allocator.
__global__ __launch_bounds__(512, 1) void k_proj(const float* __restrict__ x,
        const float* __restrict__ WtL, const float* __restrict__ WtR,
        const float* __restrict__ bl, const float* __restrict__ br,
        const float* __restrict__ att,
        float* __restrict__ XL, float* __restrict__ XRt,
        float* __restrict__ Av, float* __restrict__ Bv) {
    __shared__ __align__(16) float xst[256 * 12];   // x[c][r] at c*12+r
    __shared__ __align__(16) float mrg[3 * 4096];
    const int tid = threadIdx.x;
    const int dq = tid & 63;
    const int rq = (tid >> 6) & 1;
    const int ch = tid >> 7;
    const int R = blockIdx.x * 8;
    const int b = R >> 9, jr0 = R & 511;

    {
        const float4 xv = ((const float4*)(x + (size_t)R * 256))[tid];
        const int r = tid >> 6;
        const int c4 = (tid & 63) * 4;
        xst[(c4 + 0) * 12 + r] = xv.x;
        xst[(c4 + 1) * 12 + r] = xv.y;
        xst[(c4 + 2) * 12 + r] = xv.z;
        xst[(c4 + 3) * 12 + r] = xv.w;
    }
    __syncthreads();

    float aL[4][4], aR[4][4];
#pragma unroll
    for (int r = 0; r < 4; ++r)
#pragma unroll
        for (int k = 0; k < 4; ++k) { aL[r][k] = 0.f; aR[r][k] = 0.f; }

    const int c0 = ch * 64;
    const float* WLp = WtL + (size_t)c0 * 256 + dq * 4;
    const float* WRp = WtR + (size_t)c0 * 256 + dq * 4;

#pragma unroll
    for (int cq = 0; cq < 8; ++cq) {
        float4 wlb[8], wrb[8];                     // 16-load burst, all in flight
#pragma unroll
        for (int k = 0; k < 8; ++k) {
            wlb[k] = *(const float4*)(WLp + (size_t)(cq * 8 + k) * 256);
            wrb[k] = *(const float4*)(WRp + (size_t)(cq * 8 + k) * 256);
        }
#pragma unroll
        for (int k = 0; k < 8; ++k) {
            const float4 xv = *(const float4*)&xst[(c0 + cq * 8 + k) * 12 + rq * 4];
            const float4 wl = wlb[k], wr = wrb[k];
#define PROJ_R(r, XS)                                  \
            aL[r][0] = fmaf(XS, wl.x, aL[r][0]);       \
            aL[r][1] = fmaf(XS, wl.y, aL[r][1]);       \
            aL[r][2] = fmaf(XS, wl.z, aL[r][2]);       \
            aL[r][3] = fmaf(XS, wl.w, aL[r][3]);       \
            aR[r][0] = fmaf(XS, wr.x, aR[r][0]);       \
            aR[r][1] = fmaf(XS, wr.y, aR[r][1]);       \
            aR[r][2] = fmaf(XS, wr.z, aR[r][2]);       \
            aR[r][3] = fmaf(XS, wr.w, aR[r][3]);
            PROJ_R(0, xv.x)
            PROJ_R(1, xv.y)
            PROJ_R(2, xv.z)
            PROJ_R(3, xv.w)
#undef PROJ_R
        }
    }

    if (ch > 0) {
        float* m = &mrg[(ch - 1) * 4096];
#pragma unroll
        for (int r = 0; r < 4; ++r) {
            const int r8 = rq * 4 + r;
            *(float4*)&m[(r8 * 2 + 0) * 256 + dq * 4] = make_float4(aL[r][0], aL[r][1], aL[r][2], aL[r][3]);
            *(float4*)&m[(r8 * 2 + 1) * 256 + dq * 4] = make_float4(aR[r][0], aR[r][1], aR[r][2], aR[r][3]);
        }
    }
    __syncthreads();

    if (ch == 0) {
        const float4 bl4 = *(const float4*)&bl[dq * 4];
        const float4 br4 = *(const float4*)&br[dq * 4];
        const float4 at4 = *(const float4*)&att[dq * 4];
        float pa[4], pb[4];
#pragma unroll
        for (int r = 0; r < 4; ++r) {
            const int r8 = rq * 4 + r;
            const float4 mL0 = *(const float4*)&mrg[(r8 * 2 + 0) * 256 + dq * 4];
            const float4 mL1 = *(const float4*)&mrg[4096 + (r8 * 2 + 0) * 256 + dq * 4];
            const float4 mL2 = *(const float4*)&mrg[8192 + (r8 * 2 + 0) * 256 + dq * 4];
            const float4 mR0 = *(const float4*)&mrg[(r8 * 2 + 1) * 256 + dq * 4];
            const float4 mR1 = *(const float4*)&mrg[4096 + (r8 * 2 + 1) * 256 + dq * 4];
            const float4 mR2 = *(const float4*)&mrg[8192 + (r8 * 2 + 1) * 256 + dq * 4];
            float4 sl, sr;
            sl.x = aL[r][0] + mL0.x + mL1.x + mL2.x + bl4.x;
            sl.y = aL[r][1] + mL0.y + mL1.y + mL2.y + bl4.y;
            sl.z = aL[r][2] + mL0.z + mL1.z + mL2.z + bl4.z;
            sl.w = aL[r][3] + mL0.w + mL1.w + mL2.w + bl4.w;
            sr.x = aR[r][0] + mR0.x + mR1.x + mR2.x + br4.x;
            sr.y = aR[r][1] + mR0.y + mR1.y + mR2.y + br4.y;
            sr.z = aR[r][2] + mR0.z + mR1.z + mR2.z + br4.z;
            sr.w = aR[r][3] + mR0.w + mR1.w + mR2.w + br4.w;
            *(float4*)&XL[(size_t)(R + r8) * 256 + dq * 4] = sl;
            const size_t xrb0 = ((size_t)(b * 256 + dq * 4)) * 512 + jr0 + r8;
            XRt[xrb0 + 0 * 512] = sr.x;
            XRt[xrb0 + 1 * 512] = sr.y;
            XRt[xrb0 + 2 * 512] = sr.z;
            XRt[xrb0 + 3 * 512] = sr.w;
            pa[r] = at4.x * sl.x + at4.y * sl.y + at4.z * sl.z + at4.w * sl.w;
            pb[r] = at4.x * sr.x + at4.y * sr.y + at4.z * sr.z + at4.w * sr.w;
        }
#pragma unroll
        for (int r = 0; r < 4; ++r) {
#pragma unroll
            for (int off = 32; off; off >>= 1) {
                pa[r] += __shfl_xor(pa[r], off);
                pb[r] += __shfl_xor(pb[r], off);
            }
        }
        if (dq == 0) {
#pragma unroll
            for (int r = 0; r < 4; ++r) {
                Av[R + rq * 4 + r] = pa[r];
                Bv[R + rq * 4 + r] = pb[r];
            }
        }
    }
}

__device__ __forceinline__ void issue_chunk(const float* gp, float* lp) {
#pragma unroll
    for (int dd = 0; dd < 8; ++dd)
        GLD_LDS(gp + dd * 512, lp + dd * 256);   // 1 KB per inst: one 256-j d-row
}

// Pair kernel: 512 wgs x 256 thr; wg = 8 i x 256 j (jh = half). Wave w owns
// d-quarter [64w,64w+64): private LDS double-buffer filled by global_load_lds,
// per-wave s_waitcnt vmcnt sync — NO barriers in the hot loop. 2 wg/CU.
__global__ __launch_bounds__(256, 2) void k_pair(const float* __restrict__ XL,
        const float* __restrict__ XRt, const float* __restrict__ Av,
        const float* __restrict__ Bv, const float* __restrict__ att,
        float* __restrict__ alpha) {
    __shared__ __align__(16) float stage[4][2][2048];  // 64 KB: [wave][buf][dd*256+jl]
    __shared__ __align__(16) float xls[2048];          // 8 KB: 8 XL rows
    __shared__ __align__(16) float atts[256];          // 1 KB
    const int tid = threadIdx.x;
    const int lane = tid & 63;
    const int w = tid >> 6;            // wave id = d-quarter
    const int g = blockIdx.x;          // 0..511
    const int ig = g >> 1, jh = g & 1;
    const int R = ig * 8, b = R >> 9;
    const int j0 = jh * 256;           // j base within batch

    ((float4*)xls)[tid] = ((const float4*)(XL + (size_t)R * 256))[tid];
    ((float4*)xls)[tid + 256] = ((const float4*)(XL + (size_t)R * 256))[tid + 256];
    if (tid < 64) ((float4*)atts)[tid] = ((const float4*)att)[tid];
    __syncthreads();

    const float* gbase = XRt + ((size_t)(b * 256 + w * 64) * 512) + j0 + lane * 4;
    issue_chunk(gbase, &stage[w][0][0]);
    issue_chunk(gbase + (size_t)8 * 512, &stage[w][1][0]);

    float acc[8][4];
#pragma unroll
    for (int i = 0; i < 8; ++i)
#pragma unroll
        for (int c = 0; c < 4; ++c) acc[i][c] = 0.f;

#pragma unroll
    for (int ch = 0; ch < 8; ++ch) {
        if (ch == 7) WAIT_VM0; else WAIT_VM8;   // chunk ch landed in LDS
        const int bf = ch & 1;
        const float* sb = &stage[w][bf][0];
        const int d0 = w * 64 + ch * 8;
#pragma unroll
        for (int half = 0; half < 2; ++half) {
            const float4 a4 = *(const float4*)&atts[d0 + half * 4];   // broadcast
            float4 xlq[8];
#pragma unroll
            for (int i = 0; i < 8; ++i)
                xlq[i] = *(const float4*)&xls[i * 256 + d0 + half * 4];
#pragma unroll
            for (int d2 = 0; d2 < 4; ++d2) {
                const float4 xr = *(const float4*)&sb[(half * 4 + d2) * 256 + lane * 4];
                const float ad = d2 == 0 ? a4.x : d2 == 1 ? a4.y : d2 == 2 ? a4.z : a4.w;
#pragma unroll
                for (int i = 0; i < 8; ++i) {
                    const float xlv = d2 == 0 ? xlq[i].x : d2 == 1 ? xlq[i].y
                                    : d2 == 2 ? xlq[i].z : xlq[i].w;
                    acc[i][0] = fmaf(ad, fabsf(xlv + xr.x), acc[i][0]);  // abs = modifier
                    acc[i][1] = fmaf(ad, fabsf(xlv + xr.y), acc[i][1]);
                    acc[i][2] = fmaf(ad, fabsf(xlv + xr.z), acc[i][2]);
                    acc[i][3] = fmaf(ad, fabsf(xlv + xr.w), acc[i][3]);
                }
            }
        }
        WAIT_LGKM0;                                     // reads retired before reuse
        if (ch < 6) issue_chunk(gbase + (size_t)(ch + 2) * 8 * 512, &stage[w][bf][0]);
    }

    // merge d-quarters (2 barriers total); mrg reuses the staging region
    __syncthreads();
    float* mrg = &stage[0][0][0];
    if (w) {
        float* m = mrg + (w - 1) * 2048;
#pragma unroll
        for (int i = 0; i < 8; ++i)
            *(float4*)&m[i * 256 + lane * 4] =
                make_float4(acc[i][0], acc[i][1], acc[i][2], acc[i][3]);
    }
    __syncthreads();
    if (w == 0) {
        const float4 Bj = *(const float4*)&Bv[b * 512 + j0 + lane * 4];
#pragma unroll
        for (int i = 0; i < 8; ++i) {
            const float Ai = Av[R + i];
            const float4 p0 = *(const float4*)&mrg[i * 256 + lane * 4];
            const float4 p1 = *(const float4*)&mrg[2048 + i * 256 + lane * 4];
            const float4 p2 = *(const float4*)&mrg[4096 + i * 256 + lane * 4];
            float a0 = fmaf(0.4f, acc[i][0] + p0.x + p1.x + p2.x, 0.6f * (Ai + Bj.x));
            float a1 = fmaf(0.4f, acc[i][1] + p0.y + p1.y + p2.y, 0.6f * (Ai + Bj.y));
            float a2 = fmaf(0.4f, acc[i][2] + p0.z + p1.z + p2.z, 0.6f * (Ai + Bj.z));
            float a3 = fmaf(0.4f, acc[i][3] + p0.w + p1.w + p2.w, 0.6f * (Ai + Bj.w));
            if (!isfinite(a0)) a0 = 0.f;   // nan_to_num
            if (!isfinite(a1)) a1 = 0.f;
            if (!isfinite(a2)) a2 = 0.f;
            if (!isfinite(a3)) a3 = 0.f;
            *(float4*)&alpha[(size_t)(R + i) * 512 + j0 + lane * 4] =
                make_float4(a0, a1, a2, a3);
        }
    }
}

// 512 wgs x 256 thr; one wave per row. top-20 (jax tie-break) + softmax.
__global__ __launch_bounds__(256) void k_topk(const float* __restrict__ alpha,
                                              float* __restrict__ out) {
    const int lane = threadIdx.x & 63;
    const int row = blockIdx.x * 4 + (threadIdx.x >> 6);
    const float* ar = alpha + (size_t)row * 512;

    const float4 u0 = *(const float4*)&ar[lane * 8];
    const float4 u1 = *(const float4*)&ar[lane * 8 + 4];
    float v[8] = {u0.x, u0.y, u0.z, u0.w, u1.x, u1.y, u1.z, u1.w};  // j = lane*8+t

    float myval = 0.f, mmax = 0.f;
    int myidx = 0;
    for (int sel = 0; sel < 20; ++sel) {
        float bv = v[0]; int bt = 0;
#pragma unroll
        for (int t = 1; t < 8; ++t) { if (v[t] > bv) { bv = v[t]; bt = t; } }
        int bj = lane * 8 + bt;
#pragma unroll
        for (int off = 32; off; off >>= 1) {   // butterfly argmax, lower j wins ties
            const float ov = __shfl_xor(bv, off);
            const int   oj = __shfl_xor(bj, off);
            if (ov > bv || (ov == bv && oj < bj)) { bv = ov; bj = oj; }
        }
        if (sel == 0) mmax = bv;
        if (lane == sel) { myval = bv; myidx = bj; }
        if ((bj >> 3) == lane) {
            const int bt2 = bj & 7;
#pragma unroll
            for (int t = 0; t < 8; ++t) if (t == bt2) v[t] = -INFINITY;
        }
    }
    const float e = (lane < 20) ? expf(myval - mmax) : 0.f;
    float s = e;
#pragma unroll
    for (int off = 32; off; off >>= 1) s += __shfl_xor(s, off);
    if (lane < 20) {
        const int base = row * 20 + lane;
        const int b = row >> 9;
        out[base] = (float)row;                        // index_i
        out[40960 + base] = (float)(b * 512 + myidx);  // index_j
        out[81920 + base] = e / s;                     // attention
    }
}

extern "C" void kernel_launch(void* const* d_in, const int* in_sizes, int n_in,
                              void* d_out, int out_size, void* d_ws, size_t ws_size,
                              hipStream_t stream) {
    const float* x   = (const float*)d_in[0];
    const float* Wl  = (const float*)d_in[3];
    const float* bl  = (const float*)d_in[4];
    const float* Wr  = (const float*)d_in[5];
    const float* br  = (const float*)d_in[6];
    const float* att = (const float*)d_in[7];

    float* ws    = (float*)d_ws;
    float* WtL   = ws;
    float* WtR   = ws + 65536;
    float* alpha = ws;                 // overlaps Wt (sequential use)
    float* XL    = ws + 1048576;
    float* XRt   = ws + 1572864;
    float* Av    = ws + 2097152;
    float* Bv    = ws + 2099200;
    float* out   = (float*)d_out;

    k_transpose<<<dim3(256, 2), dim3(256), 0, stream>>>(Wl, Wr, WtL, WtR);
    k_proj<<<dim3(256), dim3(512), 0, stream>>>(x, WtL, WtR, bl, br, att, XL, XRt, Av, Bv);
    k_pair<<<dim3(512), dim3(256), 0, stream>>>(XL, XRt, Av, Bv, att, alpha);
    k_topk<<<dim3(512), dim3(256), 0, stream>>>(alpha, out);
}

// Round 10
// 124.126 us; speedup vs baseline: 1.0216x; 1.0216x over previous
//
#include <hip/hip_runtime.h>
#include <math.h>

// B=4, N=512, C=D=256, K=20, rows=2048
//
// ws layout (float offsets):
//   WtL [0, 65536)          W_l^T [c][d]
//   WtR [65536, 131072)
//   xT  [131072, 655360)    x transposed [c][row]  (256 x 2048)
//   XL  [1048576, +524288)  [row][d] row-major
//   XRt [1572864, +524288)  [b][d][j] d-major
//
// out (float): [0,40960) index_i | [40960,81920) index_j | [81920,122880) attention

// async global->LDS DMA: per-lane gptr, WAVE-UNIFORM lds base; lane l lands at
// lds_base + 16*l  (16B x 64 lanes = 1 KB per inst)
#define GLD_LDS(gp, lp)                                                        \
    __builtin_amdgcn_global_load_lds(                                          \
        (const __attribute__((address_space(1))) float*)(gp),                  \
        (__attribute__((address_space(3))) float*)(lp), 16, 0, 0)

// g<256: WtL row; g<512: WtR row; else xT column-scatter of x row g-512.
__global__ __launch_bounds__(256) void k_transpose(const float* __restrict__ x,
        const float* __restrict__ Wl, const float* __restrict__ Wr,
        float* __restrict__ WtL, float* __restrict__ WtR, float* __restrict__ xT) {
    const int g = blockIdx.x, c = threadIdx.x;
    if (g < 256)      WtL[c * 256 + g] = Wl[g * 256 + c];
    else if (g < 512) WtR[c * 256 + (g - 256)] = Wr[(g - 256) * 256 + c];
    else {
        const int r = g - 512;                       // 0..2047
        xT[(size_t)c * 2048 + r] = x[(size_t)r * 256 + c];
    }
}

// LDS-resident GEMM tile: grid 256 = side(2) x dq(4) x rb(32); 1 wg/CU.
// wg computes 64 rows x 64 d for one side. W-tile + x-tile staged by DMA
// (both contiguous per c). Thread = 4r x 4d; inner = 2 ds_read_b128 / 16 fma.
__global__ __launch_bounds__(256, 1) void k_proj(const float* __restrict__ xT,
        const float* __restrict__ WtL, const float* __restrict__ WtR,
        const float* __restrict__ bl, const float* __restrict__ br,
        float* __restrict__ XL, float* __restrict__ XRt) {
    __shared__ __align__(16) float xst[256 * 64];   // 64 KB [c][rr]
    __shared__ __align__(16) float wst[256 * 64];   // 64 KB [c][dd]
    const int tid = threadIdx.x;
    const int lane = tid & 63;
    const int wv = tid >> 6;           // 4 waves
    const int g = blockIdx.x;
    const int side = g & 1;
    const int dq = (g >> 1) & 3;
    const int rb = g >> 3;             // 0..31
    const int R = rb * 64;
    const int d0 = dq * 64;
    const int b = R >> 9;
    const float* __restrict__ W = side ? WtR : WtL;

    // stage both tiles: f4flat = (n*4+wv)*64 + lane; c = f4>>4, k = f4&15
#pragma unroll
    for (int n = 0; n < 16; ++n) {
        const int f4 = (n * 4 + wv) * 64 + lane;
        const int c = f4 >> 4, k4 = f4 & 15;
        GLD_LDS(xT + (size_t)c * 2048 + R + k4 * 4, &xst[(n * 4 + wv) * 256]);
        GLD_LDS(W + (size_t)c * 256 + d0 + k4 * 4, &wst[(n * 4 + wv) * 256]);
    }
    __syncthreads();                   // drains DMA (vmcnt 0)

    const int rt = tid & 15;           // r-quad
    const int dt = tid >> 4;           // d-quad 0..15
    float acc[4][4];
#pragma unroll
    for (int r = 0; r < 4; ++r)
#pragma unroll
        for (int k = 0; k < 4; ++k) acc[r][k] = 0.f;

    const float* xp = &xst[rt * 4];
    const float* wp = &wst[dt * 4];
#pragma unroll 8
    for (int c = 0; c < 256; ++c) {
        const float4 xv = *(const float4*)(xp + c * 64);   // 16 addr, 2-way: free
        const float4 wq = *(const float4*)(wp + c * 64);   // 4 addr x16 bcast: free
#define PROJ_R(r, XS)                              \
        acc[r][0] = fmaf(XS, wq.x, acc[r][0]);     \
        acc[r][1] = fmaf(XS, wq.y, acc[r][1]);     \
        acc[r][2] = fmaf(XS, wq.z, acc[r][2]);     \
        acc[r][3] = fmaf(XS, wq.w, acc[r][3]);
        PROJ_R(0, xv.x)
        PROJ_R(1, xv.y)
        PROJ_R(2, xv.z)
        PROJ_R(3, xv.w)
#undef PROJ_R
    }

    const float4 bias = *(const float4*)&(side ? br : bl)[d0 + dt * 4];
    if (side == 0) {
#pragma unroll
        for (int r = 0; r < 4; ++r) {
            *(float4*)&XL[(size_t)(R + rt * 4 + r) * 256 + d0 + dt * 4] =
                make_float4(acc[r][0] + bias.x, acc[r][1] + bias.y,
                            acc[r][2] + bias.z, acc[r][3] + bias.w);
        }
    } else {
        const int jr = (R & 511) + rt * 4;
#pragma unroll
        for (int k = 0; k < 4; ++k) {
            const int d = d0 + dt * 4 + k;
            const float bk = k == 0 ? bias.x : k == 1 ? bias.y : k == 2 ? bias.z : bias.w;
            *(float4*)&XRt[((size_t)(b * 256 + d)) * 512 + jr] =
                make_float4(acc[0][k] + bk, acc[1][k] + bk,
                            acc[2][k] + bk, acc[3][k] + bk);
        }
    }
}

// Fused pair + top-k + softmax (R7 structure: 256 wgs x 512 thr, register dbuf,
// 8-i reuse). Thread: jc = tid&127 (j-quad), h = tid>>7 (d-quarter, 64 d).
// Now also computes A_i (wave 0, from xls) and B_j (fused into xr stream).
__global__ __launch_bounds__(512, 2) void k_pair_topk(const float* __restrict__ XL,
        const float* __restrict__ XRt, const float* __restrict__ att,
        float* __restrict__ out) {
    __shared__ __align__(16) float xls[8 * 256];     // 8 KB
    __shared__ __align__(16) float atts[256];        // 1 KB
    __shared__ __align__(16) float mrg[3 * 4096];    // 48 KB; q0 doubles as alph
    __shared__ __align__(16) float mrgb[3 * 512];    // 6 KB: B_j partials
    __shared__ float Ais[8];
    const int tid = threadIdx.x;       // 0..511
    const int jc = tid & 127;          // j-quad index (covers all 512 j)
    const int h = tid >> 7;            // d-quarter (wave-pair uniform)
    const int g = blockIdx.x;          // 0..255
    const int R = g * 8, b = R >> 9;

    ((float4*)xls)[tid] = ((const float4*)(XL + (size_t)R * 256))[tid];
    if (tid < 64) ((float4*)atts)[tid] = ((const float4*)att)[tid];
    __syncthreads();

    // A_i = dot(att, xl_i): wave 0, lane = (i, 32d-segment)
    if (tid < 64) {
        const int ii = tid >> 3, seg = tid & 7;
        const float* xp2 = &xls[ii * 256 + seg * 32];
        const float* ap2 = &atts[seg * 32];
        float p = 0.f;
#pragma unroll
        for (int q = 0; q < 8; ++q) {
            const float4 xv = *(const float4*)(xp2 + q * 4);
            const float4 av = *(const float4*)(ap2 + q * 4);
            p += av.x * xv.x + av.y * xv.y + av.z * xv.z + av.w * xv.w;
        }
        p += __shfl_xor(p, 1); p += __shfl_xor(p, 2); p += __shfl_xor(p, 4);
        if (seg == 0) Ais[ii] = p;
    }

    const int dbase = h * 64;
    const float* __restrict__ xrp = XRt + (size_t)b * 131072 + (size_t)dbase * 512 + jc * 4;

    float acc[8][4];
#pragma unroll
    for (int i = 0; i < 8; ++i)
#pragma unroll
        for (int c = 0; c < 4; ++c) acc[i][c] = 0.f;
    float bacc[4] = {0.f, 0.f, 0.f, 0.f};            // B_j partial (this d-quarter)

    float4 bufA[8], bufB[8];
#pragma unroll
    for (int dd = 0; dd < 8; ++dd) bufA[dd] = *(const float4*)(xrp + (size_t)dd * 512);

#pragma unroll
    for (int ch = 0; ch < 8; ++ch) {
        const float4* cur = (ch & 1) ? bufB : bufA;   // static under full unroll
        float4* nxt = (ch & 1) ? bufA : bufB;
        if (ch < 7) {
            const float* p = xrp + (size_t)(ch + 1) * 8 * 512;
#pragma unroll
            for (int dd = 0; dd < 8; ++dd) nxt[dd] = *(const float4*)(p + (size_t)dd * 512);
        }
        const int d0 = dbase + ch * 8;
        const float4 at0 = *(const float4*)&atts[d0];      // LDS b128 broadcast
        const float4 at1 = *(const float4*)&atts[d0 + 4];
        // B_j partial: one fma per xr element
#define BSTEP(ATC, XR4)                                    \
        bacc[0] = fmaf(ATC, XR4.x, bacc[0]);               \
        bacc[1] = fmaf(ATC, XR4.y, bacc[1]);               \
        bacc[2] = fmaf(ATC, XR4.z, bacc[2]);               \
        bacc[3] = fmaf(ATC, XR4.w, bacc[3]);
        BSTEP(at0.x, cur[0]) BSTEP(at0.y, cur[1]) BSTEP(at0.z, cur[2]) BSTEP(at0.w, cur[3])
        BSTEP(at1.x, cur[4]) BSTEP(at1.y, cur[5]) BSTEP(at1.z, cur[6]) BSTEP(at1.w, cur[7])
#undef BSTEP
#pragma unroll
        for (int i = 0; i < 8; ++i) {
            const float4 xa = *(const float4*)&xls[i * 256 + d0];
            const float4 xb = *(const float4*)&xls[i * 256 + d0 + 4];
#define PSTEP(XLC, ATC, XR4)                                       \
            acc[i][0] = fmaf(ATC, fabsf(XLC + XR4.x), acc[i][0]);   \
            acc[i][1] = fmaf(ATC, fabsf(XLC + XR4.y), acc[i][1]);   \
            acc[i][2] = fmaf(ATC, fabsf(XLC + XR4.z), acc[i][2]);   \
            acc[i][3] = fmaf(ATC, fabsf(XLC + XR4.w), acc[i][3]);
            PSTEP(xa.x, at0.x, cur[0])
            PSTEP(xa.y, at0.y, cur[1])
            PSTEP(xa.z, at0.z, cur[2])
            PSTEP(xa.w, at0.w, cur[3])
            PSTEP(xb.x, at1.x, cur[4])
            PSTEP(xb.y, at1.y, cur[5])
            PSTEP(xb.z, at1.z, cur[6])
            PSTEP(xb.w, at1.w, cur[7])
#undef PSTEP
        }
    }

    // merge d-quarters: h=1..3 dump partials, h=0 finishes into alph(=mrg q0)
    if (h) {
        float* m = &mrg[(h - 1) * 4096];
#pragma unroll
        for (int i = 0; i < 8; ++i)
            *(float4*)&m[i * 512 + jc * 4] =
                make_float4(acc[i][0], acc[i][1], acc[i][2], acc[i][3]);
        *(float4*)&mrgb[(h - 1) * 512 + jc * 4] =
            make_float4(bacc[0], bacc[1], bacc[2], bacc[3]);
    }
    __syncthreads();
    if (h == 0) {
        const float4 bm0 = *(const float4*)&mrgb[jc * 4];
        const float4 bm1 = *(const float4*)&mrgb[512 + jc * 4];
        const float4 bm2 = *(const float4*)&mrgb[1024 + jc * 4];
        const float Bf0 = bacc[0] + bm0.x + bm1.x + bm2.x;
        const float Bf1 = bacc[1] + bm0.y + bm1.y + bm2.y;
        const float Bf2 = bacc[2] + bm0.z + bm1.z + bm2.z;
        const float Bf3 = bacc[3] + bm0.w + bm1.w + bm2.w;
#pragma unroll
        for (int i = 0; i < 8; ++i) {
            const float Ai = Ais[i];
            const float4 m0 = *(const float4*)&mrg[i * 512 + jc * 4];
            const float4 m1 = *(const float4*)&mrg[4096 + i * 512 + jc * 4];
            const float4 m2 = *(const float4*)&mrg[8192 + i * 512 + jc * 4];
            float a0 = fmaf(0.4f, acc[i][0] + m0.x + m1.x + m2.x, 0.6f * (Ai + Bf0));
            float a1 = fmaf(0.4f, acc[i][1] + m0.y + m1.y + m2.y, 0.6f * (Ai + Bf1));
            float a2 = fmaf(0.4f, acc[i][2] + m0.z + m1.z + m2.z, 0.6f * (Ai + Bf2));
            float a3 = fmaf(0.4f, acc[i][3] + m0.w + m1.w + m2.w, 0.6f * (Ai + Bf3));
            if (!isfinite(a0)) a0 = 0.f;   // nan_to_num
            if (!isfinite(a1)) a1 = 0.f;
            if (!isfinite(a2)) a2 = 0.f;
            if (!isfinite(a3)) a3 = 0.f;
            // alph aliases mrg q0: same (i,jc) slot read above, then overwritten
            *(float4*)&mrg[i * 512 + jc * 4] = make_float4(a0, a1, a2, a3);
        }
    }
    __syncthreads();

    // top-20 + softmax: wave w handles row w (8 waves, 8 rows); alph = mrg q0
    const int lane = tid & 63;
    const int i = tid >> 6;
    const float* ar = &mrg[i * 512];
    const float4 u0 = *(const float4*)&ar[lane * 8];
    const float4 u1 = *(const float4*)&ar[lane * 8 + 4];
    float v[8] = {u0.x, u0.y, u0.z, u0.w, u1.x, u1.y, u1.z, u1.w};  // j = lane*8+t

    float myval = 0.f, mmax = 0.f;
    int myidx = 0;
    for (int sel = 0; sel < 20; ++sel) {
        float bv = v[0]; int bt = 0;
#pragma unroll
        for (int t = 1; t < 8; ++t) { if (v[t] > bv) { bv = v[t]; bt = t; } }
        int bj = lane * 8 + bt;
#pragma unroll
        for (int off = 32; off; off >>= 1) {   // butterfly argmax, lower j wins ties
            const float ov = __shfl_xor(bv, off);
            const int   oj = __shfl_xor(bj, off);
            if (ov > bv || (ov == bv && oj < bj)) { bv = ov; bj = oj; }
        }
        if (sel == 0) mmax = bv;
        if (lane == sel) { myval = bv; myidx = bj; }
        if ((bj >> 3) == lane) {
            const int bt2 = bj & 7;
#pragma unroll
            for (int t = 0; t < 8; ++t) if (t == bt2) v[t] = -INFINITY;
        }
    }
    const float e = (lane < 20) ? expf(myval - mmax) : 0.f;
    float s = e;
#pragma unroll
    for (int off = 32; off; off >>= 1) s += __shfl_xor(s, off);
    if (lane < 20) {
        const int row = R + i;
        const int base = row * 20 + lane;
        out[base] = (float)row;                        // index_i
        out[40960 + base] = (float)(b * 512 + myidx);  // index_j
        out[81920 + base] = e / s;                     // attention
    }
}

extern "C" void kernel_launch(void* const* d_in, const int* in_sizes, int n_in,
                              void* d_out, int out_size, void* d_ws, size_t ws_size,
                              hipStream_t stream) {
    const float* x   = (const float*)d_in[0];
    const float* Wl  = (const float*)d_in[3];
    const float* bl  = (const float*)d_in[4];
    const float* Wr  = (const float*)d_in[5];
    const float* br  = (const float*)d_in[6];
    const float* att = (const float*)d_in[7];

    float* ws  = (float*)d_ws;
    float* WtL = ws;
    float* WtR = ws + 65536;
    float* xT  = ws + 131072;
    float* XL  = ws + 1048576;
    float* XRt = ws + 1572864;
    float* out = (float*)d_out;

    k_transpose<<<dim3(2560), dim3(256), 0, stream>>>(x, Wl, Wr, WtL, WtR, xT);
    k_proj<<<dim3(256), dim3(256), 0, stream>>>(xT, WtL, WtR, bl, br, XL, XRt);
    k_pair_topk<<<dim3(256), dim3(512), 0, stream>>>(XL, XRt, att, out);
}